// Round 1
// baseline (611.625 us; speedup 1.0000x reference)
//
#include <hip/hip_runtime.h>

typedef unsigned short ushortT;
typedef __attribute__((ext_vector_type(8))) short bf16x8;
typedef __attribute__((ext_vector_type(4))) float f32x4;

#define B_ 4
#define T_ 1000
#define C_ 1024
#define H_ 16
#define D_ 64
#define MP 4096           // padded M (4000 -> 4096)

__device__ __forceinline__ ushortT f2bf(float f) {
    unsigned u = __float_as_uint(f);
    u += 0x7fffu + ((u >> 16) & 1u);   // round-to-nearest-even
    return (ushortT)(u >> 16);
}

// ---------------- prep: cast x (fp32 [4000][1024]) -> Xb bf16 [4096][1024], pad rows zero
__global__ void cast_x_kernel(const float* __restrict__ x, ushortT* __restrict__ Xb) {
    int idx = blockIdx.x * 256 + threadIdx.x;      // one thread per 4 elements
    int e = idx * 4;
    if (e >= MP * C_) return;
    int r = e >> 10;
    ushort4 o;
    if (r < B_ * T_) {
        float4 v = *(const float4*)(x + (size_t)e);
        o.x = f2bf(v.x); o.y = f2bf(v.y); o.z = f2bf(v.z); o.w = f2bf(v.w);
    } else {
        o.x = o.y = o.z = o.w = 0;
    }
    *(ushort4*)(Xb + e) = o;
}

// ---------------- prep: transpose W [1024][N] fp32 -> Wt [N][1024] bf16
__global__ void transpose_w_kernel(const float* __restrict__ W, ushortT* __restrict__ Wt, int N) {
    __shared__ float tile[64][65];
    int k0 = blockIdx.y * 64, n0 = blockIdx.x * 64;
    int lane = threadIdx.x & 63, w4 = threadIdx.x >> 6;
#pragma unroll 4
    for (int i = 0; i < 16; ++i) {
        int row = i * 4 + w4;
        tile[row][lane] = W[(size_t)(k0 + row) * N + n0 + lane];
    }
    __syncthreads();
#pragma unroll 4
    for (int i = 0; i < 16; ++i) {
        int row = i * 4 + w4;
        Wt[(size_t)(n0 + row) * 1024 + k0 + lane] = f2bf(tile[lane][row]);
    }
}

// ---------------- MFMA GEMM: C[M][N] (fp32) = A(bf16 [M][K]) * Bt(bf16 [N][K])^T
// 128x128 tile, BK=64, 4 waves (2x2), each wave 64x64 via 4x4 mfma_f32_16x16x32_bf16.
// LDS chunk-XOR swizzle: 16B chunk c of row r holds global chunk c ^ (r&7).
#define BM 128
#define BN 128
#define BK 64

__global__ __launch_bounds__(256, 2) void gemm_bf16_kernel(
    const ushortT* __restrict__ A, const ushortT* __restrict__ Bt,
    float* __restrict__ C, int M, int N, int K, int Mstore)
{
    __shared__ ushortT As[BM * BK];   // 16 KB
    __shared__ ushortT Bs[BN * BK];   // 16 KB
    int tid = threadIdx.x;
    int wave = tid >> 6, lane = tid & 63;
    int m0 = blockIdx.y * BM;
    int n0 = blockIdx.x * BN;
    int wm = (wave >> 1) * 64;
    int wn = (wave & 1) * 64;

    f32x4 acc[4][4] = {};

    int nk = K / BK;
    for (int kt = 0; kt < nk; ++kt) {
        int k0 = kt * BK;
        __syncthreads();   // previous compute done reading LDS (also drains vmcnt)
#pragma unroll
        for (int it = 0; it < 4; ++it) {
            int gci = (wave * 4 + it) * 64 + lane;   // flat 16B-chunk id 0..1023
            int r = gci >> 3;                        // tile row 0..127
            int c = gci & 7;                         // chunk within row
            int sc = c ^ (r & 7);                    // swizzled source chunk
            const ushortT* ga = A + (size_t)(m0 + r) * K + k0 + sc * 8;
            __builtin_amdgcn_global_load_lds(
                (const __attribute__((address_space(1))) unsigned int*)ga,
                (__attribute__((address_space(3))) unsigned int*)(As + (wave * 4 + it) * 512),
                16, 0, 0);
            const ushortT* gb = Bt + (size_t)(n0 + r) * K + k0 + sc * 8;
            __builtin_amdgcn_global_load_lds(
                (const __attribute__((address_space(1))) unsigned int*)gb,
                (__attribute__((address_space(3))) unsigned int*)(Bs + (wave * 4 + it) * 512),
                16, 0, 0);
        }
        __syncthreads();   // staging visible to all waves
        int quad = lane >> 4;
#pragma unroll
        for (int s = 0; s < 2; ++s) {
            int g = s * 4 + quad;                    // global 16B chunk for this lane's k
            bf16x8 af[4], bfr[4];
#pragma unroll
            for (int mi = 0; mi < 4; ++mi) {
                int r = wm + mi * 16 + (lane & 15);
                af[mi] = *(const bf16x8*)(As + r * 64 + ((g ^ (r & 7)) * 8));
            }
#pragma unroll
            for (int ni = 0; ni < 4; ++ni) {
                int r = wn + ni * 16 + (lane & 15);
                bfr[ni] = *(const bf16x8*)(Bs + r * 64 + ((g ^ (r & 7)) * 8));
            }
#pragma unroll
            for (int mi = 0; mi < 4; ++mi)
#pragma unroll
                for (int ni = 0; ni < 4; ++ni)
                    acc[mi][ni] = __builtin_amdgcn_mfma_f32_16x16x32_bf16(
                        af[mi], bfr[ni], acc[mi][ni], 0, 0, 0);
        }
    }

    // epilogue: C/D layout col=lane&15, row=(lane>>4)*4+reg
    int quad = lane >> 4, col0 = lane & 15;
#pragma unroll
    for (int mi = 0; mi < 4; ++mi) {
#pragma unroll
        for (int j = 0; j < 4; ++j) {
            int row = m0 + wm + mi * 16 + quad * 4 + j;
            if (row < Mstore) {
                float* cp = C + (size_t)row * N + n0 + wn;
#pragma unroll
                for (int ni = 0; ni < 4; ++ni)
                    cp[ni * 16 + col0] = acc[mi][ni][j];
            }
        }
    }
}

// ---------------- RoPE in place on qkv fp32 [4000][3072] (q: cols 0..1023, k: 1024..2047)
__global__ void rope_kernel(float* __restrict__ qkv) {
    int idx = blockIdx.x * 256 + threadIdx.x;    // (r, h, pair)
    if (idx >= B_ * T_ * H_ * 32) return;
    int p = idx & 31;
    int h = (idx >> 5) & 15;
    int r = idx >> 9;
    int t = r % T_;
    // theta = 10000^(-2p/64)
    float inv = __expf((float)p * (-2.0f / 64.0f) * 9.2103403719761836f);
    float ang = (float)t * inv;
    float sn, cs;
    sincosf(ang, &sn, &cs);
    size_t base = (size_t)r * 3072 + h * 64 + p * 2;
    float2 q = *(float2*)(qkv + base);
    float2 k = *(float2*)(qkv + base + 1024);
    *(float2*)(qkv + base)        = make_float2(q.x * cs - q.y * sn, q.y * cs + q.x * sn);
    *(float2*)(qkv + base + 1024) = make_float2(k.x * cs - k.y * sn, k.y * cs + k.x * sn);
}

// ---------------- causal flash attention, fp32. block = (b, h, 16 query rows), 4 waves.
// score phase: lane = key; PV phase: lane = d (V staged transposed).
__global__ __launch_bounds__(256) void attn_kernel(
    const float* __restrict__ qkv, ushortT* __restrict__ Yb)
{
    __shared__ float kbuf[64][68];    // [key][d], 17-chunk row stride (odd) -> conflict-free b128
    __shared__ float vbufT[64][68];   // [d][key]
    __shared__ float qbuf[16][64];
    __shared__ float pbuf[16][64];

    int b = blockIdx.z, h = blockIdx.y;
    int r0 = blockIdx.x * 16;
    int tid = threadIdx.x, wave = tid >> 6, lane = tid & 63;
    const float scale = 0.125f;   // 1/sqrt(64)

    // load q rows
    {
        int e = tid * 4;
        int row = e >> 6, col = e & 63;
        int t = r0 + row;
        float4 qv = make_float4(0.f, 0.f, 0.f, 0.f);
        if (t < T_) qv = *(const float4*)(qkv + (size_t)(b * T_ + t) * 3072 + h * 64 + col);
        *(float4*)(&qbuf[row][col]) = qv;
    }

    float m_i[4], l_i[4], y[4];
#pragma unroll
    for (int i = 0; i < 4; ++i) { m_i[i] = -__builtin_inff(); l_i[i] = 0.f; y[i] = 0.f; }

    int tmax_blk = r0 + 15; if (tmax_blk > T_ - 1) tmax_blk = T_ - 1;
    int nchunks = tmax_blk / 64 + 1;

    for (int cc = 0; cc < nchunks; ++cc) {
        int j0 = cc * 64;
        __syncthreads();
        // stage K chunk and V^T chunk
        {
            int jj = tid >> 2, quad = tid & 3;
            int key = j0 + jj;
            const float* kg = qkv + (size_t)(b * T_ + key) * 3072 + 1024 + h * 64;
            const float* vg = kg + 1024;
#pragma unroll
            for (int ii = 0; ii < 4; ++ii) {
                int d0 = quad * 16 + ii * 4;
                float4 kv = make_float4(0.f, 0.f, 0.f, 0.f);
                float4 vv = make_float4(0.f, 0.f, 0.f, 0.f);
                if (key < T_) { kv = *(const float4*)(kg + d0); vv = *(const float4*)(vg + d0); }
                *(float4*)(&kbuf[jj][d0]) = kv;
                vbufT[d0 + 0][jj] = vv.x; vbufT[d0 + 1][jj] = vv.y;
                vbufT[d0 + 2][jj] = vv.z; vbufT[d0 + 3][jj] = vv.w;
            }
        }
        __syncthreads();
#pragma unroll
        for (int i = 0; i < 4; ++i) {
            int t = r0 + wave * 4 + i;
            if (t >= T_ || j0 > t) continue;
            int rowslot = wave * 4 + i;
            // score for key = j0 + lane
            float s = 0.f;
#pragma unroll
            for (int d4 = 0; d4 < 16; ++d4) {
                float4 qv = *(const float4*)(&qbuf[rowslot][d4 * 4]);
                float4 kv = *(const float4*)(&kbuf[lane][d4 * 4]);
                s += qv.x * kv.x + qv.y * kv.y + qv.z * kv.z + qv.w * kv.w;
            }
            s *= scale;
            int key = j0 + lane;
            if (key > t) s = -__builtin_inff();
            // online softmax
            float cm = s;
#pragma unroll
            for (int off = 32; off; off >>= 1) cm = fmaxf(cm, __shfl_xor(cm, off));
            float mnew = fmaxf(m_i[i], cm);
            float p = __expf(s - mnew);
            float ps = p;
#pragma unroll
            for (int off = 32; off; off >>= 1) ps += __shfl_xor(ps, off);
            float alpha = __expf(m_i[i] - mnew);
            l_i[i] = l_i[i] * alpha + ps;
            m_i[i] = mnew;
            y[i] *= alpha;
            pbuf[rowslot][lane] = p;   // same-wave write->read: wave-synchronous, safe
            // PV: lane = d
            float accv = 0.f;
#pragma unroll
            for (int j4 = 0; j4 < 16; ++j4) {
                float4 pv = *(const float4*)(&pbuf[rowslot][j4 * 4]);
                float4 vv = *(const float4*)(&vbufT[lane][j4 * 4]);
                accv += pv.x * vv.x + pv.y * vv.y + pv.z * vv.z + pv.w * vv.w;
            }
            y[i] += accv;
        }
    }
    // write output (bf16) into Yb [4096][1024]; lane = d
#pragma unroll
    for (int i = 0; i < 4; ++i) {
        int t = r0 + wave * 4 + i;
        if (t >= T_) continue;
        float val = y[i] / l_i[i];
        Yb[(size_t)(b * T_ + t) * 1024 + h * 64 + lane] = f2bf(val);
    }
}

extern "C" void kernel_launch(void* const* d_in, const int* in_sizes, int n_in,
                              void* d_out, int out_size, void* d_ws, size_t ws_size,
                              hipStream_t stream) {
    const float* x      = (const float*)d_in[0];
    // d_in[1] = attn_mask (causal tril) — structure known, unused
    const float* W_attn = (const float*)d_in[2];
    const float* W_proj = (const float*)d_in[3];
    float* out = (float*)d_out;

    uintptr_t w = (uintptr_t)d_ws;
    ushortT* Xb  = (ushortT*)(w);                    //  8,388,608 B  bf16 [4096][1024]
    ushortT* Wat = (ushortT*)(w + 8388608);          //  6,291,456 B  bf16 [3072][1024]
    ushortT* Wpt = (ushortT*)(w + 14680064);         //  2,097,152 B  bf16 [1024][1024]
    float*   qkv = (float*)  (w + 16777216);         // 50,331,648 B  fp32 [4096][3072]
    ushortT* Yb  = (ushortT*)(w + 67108864);         //  8,388,608 B  bf16 [4096][1024]
    // total 75,497,472 B

    // prep
    cast_x_kernel<<<dim3((MP * C_ / 4 + 255) / 256), dim3(256), 0, stream>>>(x, Xb);
    transpose_w_kernel<<<dim3(3072 / 64, 1024 / 64), dim3(256), 0, stream>>>(W_attn, Wat, 3072);
    transpose_w_kernel<<<dim3(1024 / 64, 1024 / 64), dim3(256), 0, stream>>>(W_proj, Wpt, 1024);

    // QKV = Xb @ Wat^T  -> fp32 [4096][3072]
    gemm_bf16_kernel<<<dim3(3072 / BN, MP / BM), dim3(256), 0, stream>>>(
        Xb, Wat, qkv, MP, 3072, 1024, MP);

    // RoPE on q,k
    rope_kernel<<<dim3((B_ * T_ * H_ * 32 + 255) / 256), dim3(256), 0, stream>>>(qkv);

    // attention -> Yb bf16
    attn_kernel<<<dim3((T_ + 15) / 16, H_, B_), dim3(256), 0, stream>>>(qkv, Yb);

    // out = Yb @ Wpt^T  (store only valid 4000 rows)
    gemm_bf16_kernel<<<dim3(1024 / BN, MP / BM), dim3(256), 0, stream>>>(
        Yb, Wpt, out, MP, 1024, 1024, B_ * T_);
}

// Round 2
// 205.017 us; speedup vs baseline: 2.9833x; 2.9833x over previous
//
#include <hip/hip_runtime.h>

typedef unsigned short ushortT;
typedef __attribute__((ext_vector_type(8))) short bf16x8;
typedef __attribute__((ext_vector_type(4))) float f32x4;

#define B_ 4
#define T_ 1000
#define C_ 1024
#define H_ 16
#define D_ 64
#define MP 4096           // padded M (4000 -> 4096)

__device__ __forceinline__ ushortT f2bf(float f) {
    unsigned u = __float_as_uint(f);
    u += 0x7fffu + ((u >> 16) & 1u);   // round-to-nearest-even
    return (ushortT)(u >> 16);
}
__device__ __forceinline__ float bf2f(ushortT u) {
    return __uint_as_float((unsigned)u << 16);
}

// ---------------- prep: cast x (fp32 [4000][1024]) -> Xb bf16 [4096][1024], pad rows zero
__global__ void cast_x_kernel(const float* __restrict__ x, ushortT* __restrict__ Xb) {
    int idx = blockIdx.x * 256 + threadIdx.x;      // one thread per 4 elements
    int e = idx * 4;
    if (e >= MP * C_) return;
    int r = e >> 10;
    ushort4 o;
    if (r < B_ * T_) {
        float4 v = *(const float4*)(x + (size_t)e);
        o.x = f2bf(v.x); o.y = f2bf(v.y); o.z = f2bf(v.z); o.w = f2bf(v.w);
    } else {
        o.x = o.y = o.z = o.w = 0;
    }
    *(ushort4*)(Xb + e) = o;
}

// ---------------- prep: transpose W [1024][N] fp32 -> Wt [N][1024] bf16
__global__ void transpose_w_kernel(const float* __restrict__ W, ushortT* __restrict__ Wt, int N) {
    __shared__ float tile[64][65];
    int k0 = blockIdx.y * 64, n0 = blockIdx.x * 64;
    int lane = threadIdx.x & 63, w4 = threadIdx.x >> 6;
#pragma unroll 4
    for (int i = 0; i < 16; ++i) {
        int row = i * 4 + w4;
        tile[row][lane] = W[(size_t)(k0 + row) * N + n0 + lane];
    }
    __syncthreads();
#pragma unroll 4
    for (int i = 0; i < 16; ++i) {
        int row = i * 4 + w4;
        Wt[(size_t)(n0 + row) * 1024 + k0 + lane] = f2bf(tile[lane][row]);
    }
}

// ---------------- MFMA GEMM: C[M][N] = A(bf16 [M][K]) * Bt(bf16 [N][K])^T
// 128x128 tile, BK=64, 4 waves (2x2), each wave 64x64 via 4x4 mfma_f32_16x16x32_bf16.
// LDS chunk-XOR swizzle: 16B chunk slot c of row r holds global chunk c ^ (r&7).
#define BM 128
#define BN 128
#define BK 64

__device__ __forceinline__ void gemm_store(float* p, float v)   { *p = v; }
__device__ __forceinline__ void gemm_store(ushortT* p, float v) { *p = f2bf(v); }

template <typename OutT>
__global__ __launch_bounds__(256, 2) void gemm_bf16_kernel(
    const ushortT* __restrict__ A, const ushortT* __restrict__ Bt,
    OutT* __restrict__ C, int M, int N, int K, int Mstore)
{
    __shared__ ushortT As[BM * BK];   // 16 KB
    __shared__ ushortT Bs[BN * BK];   // 16 KB
    int tid = threadIdx.x;
    int wave = tid >> 6, lane = tid & 63;
    int m0 = blockIdx.y * BM;
    int n0 = blockIdx.x * BN;
    int wm = (wave >> 1) * 64;
    int wn = (wave & 1) * 64;

    f32x4 acc[4][4] = {};

    int nk = K / BK;
    for (int kt = 0; kt < nk; ++kt) {
        int k0 = kt * BK;
        __syncthreads();
#pragma unroll
        for (int it = 0; it < 4; ++it) {
            int gci = (wave * 4 + it) * 64 + lane;   // flat 16B-chunk id 0..1023
            int r = gci >> 3;
            int c = gci & 7;
            int sc = c ^ (r & 7);
            const ushortT* ga = A + (size_t)(m0 + r) * K + k0 + sc * 8;
            __builtin_amdgcn_global_load_lds(
                (const __attribute__((address_space(1))) unsigned int*)ga,
                (__attribute__((address_space(3))) unsigned int*)(As + (wave * 4 + it) * 512),
                16, 0, 0);
            const ushortT* gb = Bt + (size_t)(n0 + r) * K + k0 + sc * 8;
            __builtin_amdgcn_global_load_lds(
                (const __attribute__((address_space(1))) unsigned int*)gb,
                (__attribute__((address_space(3))) unsigned int*)(Bs + (wave * 4 + it) * 512),
                16, 0, 0);
        }
        __syncthreads();
        int quad = lane >> 4;
#pragma unroll
        for (int s = 0; s < 2; ++s) {
            int g = s * 4 + quad;
            bf16x8 af[4], bfr[4];
#pragma unroll
            for (int mi = 0; mi < 4; ++mi) {
                int r = wm + mi * 16 + (lane & 15);
                af[mi] = *(const bf16x8*)(As + r * 64 + ((g ^ (r & 7)) * 8));
            }
#pragma unroll
            for (int ni = 0; ni < 4; ++ni) {
                int r = wn + ni * 16 + (lane & 15);
                bfr[ni] = *(const bf16x8*)(Bs + r * 64 + ((g ^ (r & 7)) * 8));
            }
#pragma unroll
            for (int mi = 0; mi < 4; ++mi)
#pragma unroll
                for (int ni = 0; ni < 4; ++ni)
                    acc[mi][ni] = __builtin_amdgcn_mfma_f32_16x16x32_bf16(
                        af[mi], bfr[ni], acc[mi][ni], 0, 0, 0);
        }
    }

    int quad = lane >> 4, col0 = lane & 15;
#pragma unroll
    for (int mi = 0; mi < 4; ++mi) {
#pragma unroll
        for (int j = 0; j < 4; ++j) {
            int row = m0 + wm + mi * 16 + quad * 4 + j;
            if (row < Mstore) {
                OutT* cp = C + (size_t)row * N + n0 + wn;
#pragma unroll
                for (int ni = 0; ni < 4; ++ni)
                    gemm_store(cp + ni * 16 + col0, acc[mi][ni][j]);
            }
        }
    }
}

// ---------------- RoPE + pack: qkvb bf16 [4000][3072] -> Qb,Kb bf16 [b][h][1024][64] (zero-pad)
__global__ void rope_pack_kernel(const ushortT* __restrict__ qkvb,
                                 ushortT* __restrict__ Qb, ushortT* __restrict__ Kb) {
    int idx = blockIdx.x * 256 + threadIdx.x;   // p fastest (32), h (16), t (1024), b (4)
    int p = idx & 31;
    int h = (idx >> 5) & 15;
    int t = (idx >> 9) & 1023;
    int b = idx >> 19;
    ushort2 qres = make_ushort2(0, 0), kres = make_ushort2(0, 0);
    if (t < T_) {
        const ushortT* src = qkvb + (size_t)(b * T_ + t) * 3072 + h * 64 + 2 * p;
        ushort2 qu = *(const ushort2*)(src);
        ushort2 ku = *(const ushort2*)(src + 1024);
        float q0 = bf2f(qu.x), q1 = bf2f(qu.y);
        float k0 = bf2f(ku.x), k1 = bf2f(ku.y);
        // theta = 10000^(-p/32) = exp(-p * ln(10000)/32)
        float theta = __expf(-(float)p * 0.28782313662425572f);
        float ang = (float)t * theta;
        float sn, cs;
        sincosf(ang, &sn, &cs);
        qres = make_ushort2(f2bf(q0 * cs - q1 * sn), f2bf(q1 * cs + q0 * sn));
        kres = make_ushort2(f2bf(k0 * cs - k1 * sn), f2bf(k1 * cs + k0 * sn));
    }
    size_t dst = ((size_t)(b * 16 + h) << 16) + (size_t)t * 64 + 2 * p;
    *(ushort2*)(Qb + dst) = qres;
    *(ushort2*)(Kb + dst) = kres;
}

// ---------------- V transpose: qkvb v-cols -> Vtb bf16 [b][h][64][1024] (zero-pad in t)
__global__ void vtrans_kernel(const ushortT* __restrict__ qkvb, ushortT* __restrict__ Vtb) {
    __shared__ ushortT tile[64 * 72];
    int t0 = blockIdx.x * 64;
    int h = blockIdx.y, b = blockIdx.z;
    int tid = threadIdx.x;
    int row = tid >> 2, c4 = tid & 3;
    int t = t0 + row;
    bf16x8 v0 = {}, v1 = {};
    if (t < T_) {
        const ushortT* src = qkvb + (size_t)(b * T_ + t) * 3072 + 2048 + h * 64 + c4 * 16;
        v0 = *(const bf16x8*)(src);
        v1 = *(const bf16x8*)(src + 8);
    }
    *(bf16x8*)(tile + row * 72 + c4 * 16) = v0;
    *(bf16x8*)(tile + row * 72 + c4 * 16 + 8) = v1;
    __syncthreads();
    int d = tid >> 2, tcol = (tid & 3) * 16;
    ushortT outv[16];
#pragma unroll
    for (int i = 0; i < 16; ++i) outv[i] = tile[(tcol + i) * 72 + d];
    ushortT* dst = Vtb + ((size_t)(b * 16 + h) << 16) + (size_t)d * 1024 + t0 + tcol;
    *(bf16x8*)(dst) = *(bf16x8*)(outv);
    *(bf16x8*)(dst + 8) = *(bf16x8*)(outv + 8);
}

// ---------------- MFMA flash attention
// block = (b, h, 64 q rows), 4 waves x 16 rows. K-chunks of 64, XOR-swizzled LDS staging.
// A-frag: A[m=lane&15][k=quad*8+j]; B-frag: B[k=quad*8+j][n=lane&15]; C/D: col=lane&15,row=quad*4+reg
#define PSTR 72
__global__ __launch_bounds__(256) void attn_mfma_kernel(
    const ushortT* __restrict__ Qb, const ushortT* __restrict__ Kb,
    const ushortT* __restrict__ Vtb, ushortT* __restrict__ Yb)
{
    __shared__ ushortT Ks[64 * 64];     // [key][d], xor-swizzled 16B chunks (8 KB)
    __shared__ ushortT Vs[64 * 64];     // [d][key], xor-swizzled (8 KB)
    __shared__ ushortT Ps[64 * PSTR];   // [local q][key], padded stride (9 KB)

    int q0 = blockIdx.x * 64;
    int h = blockIdx.y, b = blockIdx.z;
    int bh = b * 16 + h;
    int tid = threadIdx.x, wave = tid >> 6, lane = tid & 63;
    int col0 = lane & 15, quad = lane >> 4;

    const ushortT* Kbh  = Kb  + ((size_t)bh << 16);
    const ushortT* Vtbh = Vtb + ((size_t)bh << 16);

    // Q fragment: rows q0 + wave*16 + (lane&15), two 32-d k-steps
    const ushortT* qrowp = Qb + ((size_t)bh << 16) + (size_t)(q0 + wave * 16 + col0) * 64;
    bf16x8 aq[2];
    aq[0] = *(const bf16x8*)(qrowp + quad * 8);
    aq[1] = *(const bf16x8*)(qrowp + 32 + quad * 8);

    f32x4 o[4] = {};
    float m_i[4], l_i[4];
#pragma unroll
    for (int r = 0; r < 4; ++r) { m_i[r] = -3.0e38f; l_i[r] = 0.f; }

    int nchunks = blockIdx.x + 1;
    for (int cc = 0; cc < nchunks; ++cc) {
        int j0 = cc * 64;
        __syncthreads();   // prior reads of Ks/Vs done (drains vmcnt+lgkm)
#pragma unroll
        for (int it = 0; it < 2; ++it) {
            int gci = (wave * 2 + it) * 64 + lane;   // chunk id 0..511
            int r = gci >> 3;
            int c = gci & 7;
            int sc = c ^ (r & 7);
            const ushortT* gk = Kbh + (size_t)(j0 + r) * 64 + sc * 8;
            __builtin_amdgcn_global_load_lds(
                (const __attribute__((address_space(1))) unsigned int*)gk,
                (__attribute__((address_space(3))) unsigned int*)(Ks + (wave * 2 + it) * 512),
                16, 0, 0);
            const ushortT* gv = Vtbh + (size_t)r * 1024 + j0 + sc * 8;
            __builtin_amdgcn_global_load_lds(
                (const __attribute__((address_space(1))) unsigned int*)gv,
                (__attribute__((address_space(3))) unsigned int*)(Vs + (wave * 2 + it) * 512),
                16, 0, 0);
        }
        __syncthreads();

        // ---- scores: S = Q K^T  (16 q x 64 keys per wave)
        f32x4 sc4[4] = {};
#pragma unroll
        for (int s = 0; s < 2; ++s) {
#pragma unroll
            for (int nt = 0; nt < 4; ++nt) {
                int r = nt * 16 + col0;
                bf16x8 bk = *(const bf16x8*)(Ks + r * 64 + (((s * 4 + quad) ^ (r & 7)) * 8));
                sc4[nt] = __builtin_amdgcn_mfma_f32_16x16x32_bf16(aq[s], bk, sc4[nt], 0, 0, 0);
            }
        }

        // ---- online softmax (fp32), rows = quad*4+reg, cols = nt*16+col0
        bool last = (cc == nchunks - 1);
#pragma unroll
        for (int reg = 0; reg < 4; ++reg) {
            int q = q0 + wave * 16 + quad * 4 + reg;
            float mx = -3.0e38f;
#pragma unroll
            for (int nt = 0; nt < 4; ++nt) {
                float s = sc4[nt][reg] * 0.125f;
                if (last && (j0 + nt * 16 + col0) > q) s = -3.0e38f;
                sc4[nt][reg] = s;
                mx = fmaxf(mx, s);
            }
            mx = fmaxf(mx, __shfl_xor(mx, 1));
            mx = fmaxf(mx, __shfl_xor(mx, 2));
            mx = fmaxf(mx, __shfl_xor(mx, 4));
            mx = fmaxf(mx, __shfl_xor(mx, 8));
            float mnew = fmaxf(m_i[reg], mx);
            float sum = 0.f;
#pragma unroll
            for (int nt = 0; nt < 4; ++nt) {
                float p = __expf(sc4[nt][reg] - mnew);
                sc4[nt][reg] = p;
                sum += p;
            }
            sum += __shfl_xor(sum, 1);
            sum += __shfl_xor(sum, 2);
            sum += __shfl_xor(sum, 4);
            sum += __shfl_xor(sum, 8);
            float alpha = __expf(m_i[reg] - mnew);
            m_i[reg] = mnew;
            l_i[reg] = l_i[reg] * alpha + sum;
#pragma unroll
            for (int nt = 0; nt < 4; ++nt) o[nt][reg] *= alpha;
            // write P row to LDS (C-layout -> A-layout round trip)
#pragma unroll
            for (int nt = 0; nt < 4; ++nt)
                Ps[(wave * 16 + quad * 4 + reg) * PSTR + nt * 16 + col0] = f2bf(sc4[nt][reg]);
        }

        // ---- PV: O += P V   (wave-local Ps; compiler inserts lgkm wait)
#pragma unroll
        for (int s = 0; s < 2; ++s) {
            bf16x8 ap = *(const bf16x8*)(Ps + (wave * 16 + col0) * PSTR + s * 32 + quad * 8);
#pragma unroll
            for (int nt = 0; nt < 4; ++nt) {
                int r = nt * 16 + col0;
                bf16x8 bv = *(const bf16x8*)(Vs + r * 64 + (((s * 4 + quad) ^ (r & 7)) * 8));
                o[nt] = __builtin_amdgcn_mfma_f32_16x16x32_bf16(ap, bv, o[nt], 0, 0, 0);
            }
        }
    }

    // ---- epilogue: Yb[b*1000+q][h*64+d] bf16
#pragma unroll
    for (int reg = 0; reg < 4; ++reg) {
        int q = q0 + wave * 16 + quad * 4 + reg;
        if (q < T_) {
            float inv_l = 1.0f / l_i[reg];
            ushortT* yp = Yb + (size_t)(b * T_ + q) * 1024 + h * 64;
#pragma unroll
            for (int nt = 0; nt < 4; ++nt)
                yp[nt * 16 + col0] = f2bf(o[nt][reg] * inv_l);
        }
    }
}

extern "C" void kernel_launch(void* const* d_in, const int* in_sizes, int n_in,
                              void* d_out, int out_size, void* d_ws, size_t ws_size,
                              hipStream_t stream) {
    const float* x      = (const float*)d_in[0];
    // d_in[1] = attn_mask (causal tril) — structure known, unused
    const float* W_attn = (const float*)d_in[2];
    const float* W_proj = (const float*)d_in[3];
    float* out = (float*)d_out;

    uintptr_t w = (uintptr_t)d_ws;
    ushortT* Xb   = (ushortT*)(w);                   //  8,388,608 B  bf16 [4096][1024]
    ushortT* Wat  = (ushortT*)(w + 8388608);         //  6,291,456 B  bf16 [3072][1024]
    ushortT* Wpt  = (ushortT*)(w + 14680064);        //  2,097,152 B  bf16 [1024][1024]
    ushortT* qkvb = (ushortT*)(w + 16777216);        // 25,165,824 B  bf16 [4096][3072]
    ushortT* Qb   = (ushortT*)(w + 41943040);        //  8,388,608 B  bf16 [64bh][1024][64]
    ushortT* Kb   = (ushortT*)(w + 50331648);        //  8,388,608 B
    ushortT* Vtb  = (ushortT*)(w + 58720256);        //  8,388,608 B  bf16 [64bh][64][1024]
    ushortT* Yb   = (ushortT*)(w + 67108864);        //  8,388,608 B  bf16 [4096][1024]
    // total 75,497,472 B (same footprint as R1 — known to fit)

    // prep
    cast_x_kernel<<<dim3((MP * C_ / 4 + 255) / 256), dim3(256), 0, stream>>>(x, Xb);
    transpose_w_kernel<<<dim3(3072 / 64, 1024 / 64), dim3(256), 0, stream>>>(W_attn, Wat, 3072);
    transpose_w_kernel<<<dim3(1024 / 64, 1024 / 64), dim3(256), 0, stream>>>(W_proj, Wpt, 1024);

    // QKV = Xb @ Wat^T -> bf16 [4096][3072]
    gemm_bf16_kernel<ushortT><<<dim3(3072 / BN, MP / BM), dim3(256), 0, stream>>>(
        Xb, Wat, qkvb, MP, 3072, 1024, MP);

    // RoPE + pack q,k ; transpose v
    rope_pack_kernel<<<dim3(B_ * 1024 * H_ * 32 / 256), dim3(256), 0, stream>>>(qkvb, Qb, Kb);
    vtrans_kernel<<<dim3(16, H_, B_), dim3(256), 0, stream>>>(qkvb, Vtb);

    // MFMA flash attention -> Yb bf16
    attn_mfma_kernel<<<dim3(16, H_, B_), dim3(256), 0, stream>>>(Qb, Kb, Vtb, Yb);

    // out = Yb @ Wpt^T (fp32, store 4000 rows)
    gemm_bf16_kernel<float><<<dim3(1024 / BN, MP / BM), dim3(256), 0, stream>>>(
        Yb, Wpt, out, MP, 1024, 1024, B_ * T_);
}

// Round 3
// 169.645 us; speedup vs baseline: 3.6053x; 1.2085x over previous
//
#include <hip/hip_runtime.h>

typedef unsigned short ushortT;
typedef __attribute__((ext_vector_type(8))) short bf16x8;
typedef __attribute__((ext_vector_type(4))) float f32x4;

#define B_ 4
#define T_ 1000
#define C_ 1024
#define H_ 16
#define D_ 64
#define MP 4096           // padded M (4000 -> 4096)

__device__ __forceinline__ ushortT f2bf(float f) {
    unsigned u = __float_as_uint(f);
    u += 0x7fffu + ((u >> 16) & 1u);   // round-to-nearest-even
    return (ushortT)(u >> 16);
}
__device__ __forceinline__ float bf2f(ushortT u) {
    return __uint_as_float((unsigned)u << 16);
}
__device__ __forceinline__ float fast_exp2(float x) {
#if __has_builtin(__builtin_amdgcn_exp2f)
    return __builtin_amdgcn_exp2f(x);
#else
    return exp2f(x);
#endif
}

// ---------------- prep: cast x (fp32 [4000][1024]) -> Xb bf16 [4096][1024], pad rows zero
__global__ void cast_x_kernel(const float* __restrict__ x, ushortT* __restrict__ Xb) {
    int idx = blockIdx.x * 256 + threadIdx.x;
    int e = idx * 4;
    if (e >= MP * C_) return;
    int r = e >> 10;
    ushort4 o;
    if (r < B_ * T_) {
        float4 v = *(const float4*)(x + (size_t)e);
        o.x = f2bf(v.x); o.y = f2bf(v.y); o.z = f2bf(v.z); o.w = f2bf(v.w);
    } else {
        o.x = o.y = o.z = o.w = 0;
    }
    *(ushort4*)(Xb + e) = o;
}

// ---------------- prep: transpose W [1024][N] fp32 -> Wt [N][1024] bf16
__global__ void transpose_w_kernel(const float* __restrict__ W, ushortT* __restrict__ Wt, int N) {
    __shared__ float tile[64][65];
    int k0 = blockIdx.y * 64, n0 = blockIdx.x * 64;
    int lane = threadIdx.x & 63, w4 = threadIdx.x >> 6;
#pragma unroll 4
    for (int i = 0; i < 16; ++i) {
        int row = i * 4 + w4;
        tile[row][lane] = W[(size_t)(k0 + row) * N + n0 + lane];
    }
    __syncthreads();
#pragma unroll 4
    for (int i = 0; i < 16; ++i) {
        int row = i * 4 + w4;
        Wt[(size_t)(n0 + row) * 1024 + k0 + lane] = f2bf(tile[lane][row]);
    }
}

// ---------------- MFMA GEMM: C[M][N] = A(bf16 [M][K]) * Bt(bf16 [N][K])^T
#define BM 128
#define BN 128
#define BK 64

__device__ __forceinline__ void gemm_store(float* p, float v)   { *p = v; }
__device__ __forceinline__ void gemm_store(ushortT* p, float v) { *p = f2bf(v); }

template <typename OutT>
__global__ __launch_bounds__(256, 2) void gemm_bf16_kernel(
    const ushortT* __restrict__ A, const ushortT* __restrict__ Bt,
    OutT* __restrict__ C, int M, int N, int K, int Mstore)
{
    __shared__ ushortT As[BM * BK];
    __shared__ ushortT Bs[BN * BK];
    int tid = threadIdx.x;
    int wave = tid >> 6, lane = tid & 63;
    int m0 = blockIdx.y * BM;
    int n0 = blockIdx.x * BN;
    int wm = (wave >> 1) * 64;
    int wn = (wave & 1) * 64;

    f32x4 acc[4][4] = {};

    int nk = K / BK;
    for (int kt = 0; kt < nk; ++kt) {
        int k0 = kt * BK;
        __syncthreads();
#pragma unroll
        for (int it = 0; it < 4; ++it) {
            int gci = (wave * 4 + it) * 64 + lane;
            int r = gci >> 3;
            int c = gci & 7;
            int sc = c ^ (r & 7);
            const ushortT* ga = A + (size_t)(m0 + r) * K + k0 + sc * 8;
            __builtin_amdgcn_global_load_lds(
                (const __attribute__((address_space(1))) unsigned int*)ga,
                (__attribute__((address_space(3))) unsigned int*)(As + (wave * 4 + it) * 512),
                16, 0, 0);
            const ushortT* gb = Bt + (size_t)(n0 + r) * K + k0 + sc * 8;
            __builtin_amdgcn_global_load_lds(
                (const __attribute__((address_space(1))) unsigned int*)gb,
                (__attribute__((address_space(3))) unsigned int*)(Bs + (wave * 4 + it) * 512),
                16, 0, 0);
        }
        __syncthreads();
        int quad = lane >> 4;
#pragma unroll
        for (int s = 0; s < 2; ++s) {
            int g = s * 4 + quad;
            bf16x8 af[4], bfr[4];
#pragma unroll
            for (int mi = 0; mi < 4; ++mi) {
                int r = wm + mi * 16 + (lane & 15);
                af[mi] = *(const bf16x8*)(As + r * 64 + ((g ^ (r & 7)) * 8));
            }
#pragma unroll
            for (int ni = 0; ni < 4; ++ni) {
                int r = wn + ni * 16 + (lane & 15);
                bfr[ni] = *(const bf16x8*)(Bs + r * 64 + ((g ^ (r & 7)) * 8));
            }
#pragma unroll
            for (int mi = 0; mi < 4; ++mi)
#pragma unroll
                for (int ni = 0; ni < 4; ++ni)
                    acc[mi][ni] = __builtin_amdgcn_mfma_f32_16x16x32_bf16(
                        af[mi], bfr[ni], acc[mi][ni], 0, 0, 0);
        }
    }

    int quad = lane >> 4, col0 = lane & 15;
#pragma unroll
    for (int mi = 0; mi < 4; ++mi) {
#pragma unroll
        for (int j = 0; j < 4; ++j) {
            int row = m0 + wm + mi * 16 + quad * 4 + j;
            if (row < Mstore) {
                OutT* cp = C + (size_t)row * N + n0 + wn;
#pragma unroll
                for (int ni = 0; ni < 4; ++ni)
                    gemm_store(cp + ni * 16 + col0, acc[mi][ni][j]);
            }
        }
    }
}

// ---------------- RoPE + pack: qkvb bf16 -> Qb (pre-scaled by 0.125*log2e), Kb  [bh][1024][64]
#define QSCALE 0.18033688011112042f   // 0.125 * log2(e)
__global__ void rope_pack_kernel(const ushortT* __restrict__ qkvb,
                                 ushortT* __restrict__ Qb, ushortT* __restrict__ Kb) {
    int idx = blockIdx.x * 256 + threadIdx.x;   // p (32), h (16), t (1024), b (4)
    int p = idx & 31;
    int h = (idx >> 5) & 15;
    int t = (idx >> 9) & 1023;
    int b = idx >> 19;
    ushort2 qres = make_ushort2(0, 0), kres = make_ushort2(0, 0);
    if (t < T_) {
        const ushortT* src = qkvb + (size_t)(b * T_ + t) * 3072 + h * 64 + 2 * p;
        ushort2 qu = *(const ushort2*)(src);
        ushort2 ku = *(const ushort2*)(src + 1024);
        float q0 = bf2f(qu.x), q1 = bf2f(qu.y);
        float k0 = bf2f(ku.x), k1 = bf2f(ku.y);
        float theta = __expf(-(float)p * 0.28782313662425572f);  // 10000^(-p/32)
        float ang = (float)t * theta;
        float sn, cs;
        sincosf(ang, &sn, &cs);
        float csq = cs * QSCALE, snq = sn * QSCALE;
        qres = make_ushort2(f2bf(q0 * csq - q1 * snq), f2bf(q1 * csq + q0 * snq));
        kres = make_ushort2(f2bf(k0 * cs - k1 * sn), f2bf(k1 * cs + k0 * sn));
    }
    size_t dst = ((size_t)(b * 16 + h) << 16) + (size_t)t * 64 + 2 * p;
    *(ushort2*)(Qb + dst) = qres;
    *(ushort2*)(Kb + dst) = kres;
}

// ---------------- V transpose with per-128 key permutation pi(k) = (k&15)*8 + (k>>4)
// Vtb[bh][d][kc*128 + pos] = V[kc*128 + pi_inv(pos)][d],  pi_inv(pos) = (pos&7)*16 + (pos>>3)
__global__ void vtrans_kernel(const ushortT* __restrict__ qkvb, ushortT* __restrict__ Vtb) {
    __shared__ __align__(16) ushortT tile[128 * 72];
    int t0 = blockIdx.x * 128;
    int h = blockIdx.y, b = blockIdx.z;
    int tid = threadIdx.x;
#pragma unroll
    for (int it = 0; it < 4; ++it) {
        int cid = it * 256 + tid;
        int r = cid >> 3, c = cid & 7;
        int t = t0 + r;
        bf16x8 v = {};
        if (t < T_) v = *(const bf16x8*)(qkvb + (size_t)(b * T_ + t) * 3072 + 2048 + h * 64 + c * 8);
        *(bf16x8*)(tile + r * 72 + c * 8) = v;
    }
    __syncthreads();
    int bh = b * 16 + h;
#pragma unroll
    for (int it = 0; it < 4; ++it) {
        int u = it * 256 + tid;
        int d = u >> 4, c = u & 15;
        ushortT tmp[8];
#pragma unroll
        for (int j = 0; j < 8; ++j) tmp[j] = tile[(j * 16 + c) * 72 + d];
        *(bf16x8*)(Vtb + ((size_t)bh << 16) + (size_t)d * 1024 + t0 + c * 8) = *(bf16x8*)tmp;
    }
}

// ---------------- MFMA flash attention, fixed-max softmax, 128-key chunks
// block = (bh, 64 q rows), 4 waves x 16 rows. Q pre-scaled so p = exp2(score).
#define PSTR 136
template <bool LAST>
__device__ __forceinline__ void softmax_store(f32x4* sc4, ushortT* Ps,
                                              int wave, int quad, int col0,
                                              int q0, int j0) {
#pragma unroll
    for (int reg = 0; reg < 4; ++reg) {
        int m = quad * 4 + reg;
        int q = q0 + wave * 16 + m;
        float pv[8];
#pragma unroll
        for (int nt = 0; nt < 8; ++nt) {
            float p = fast_exp2(sc4[nt][reg]);
            if (LAST && (j0 + nt * 16 + col0) > q) p = 0.f;
            pv[nt] = p;
        }
        int4 pk;   // truncating f32->bf16 pair pack via v_perm
        pk.x = __builtin_amdgcn_perm(__float_as_uint(pv[1]), __float_as_uint(pv[0]), 0x07060302u);
        pk.y = __builtin_amdgcn_perm(__float_as_uint(pv[3]), __float_as_uint(pv[2]), 0x07060302u);
        pk.z = __builtin_amdgcn_perm(__float_as_uint(pv[5]), __float_as_uint(pv[4]), 0x07060302u);
        pk.w = __builtin_amdgcn_perm(__float_as_uint(pv[7]), __float_as_uint(pv[6]), 0x07060302u);
        *(int4*)(Ps + (wave * 16 + m) * PSTR + col0 * 8) = pk;
    }
}

__global__ __launch_bounds__(256, 3) void attn_mfma_kernel(
    const ushortT* __restrict__ Qb, const ushortT* __restrict__ Kb,
    const ushortT* __restrict__ Vtb, ushortT* __restrict__ Yb)
{
    __shared__ __align__(16) ushortT Ks[128 * 64];   // [key][d], xor chunk swizzle (16 KB)
    __shared__ __align__(16) ushortT Vs[64 * 128];   // [d][kpos], xor chunk swizzle (16 KB)
    __shared__ __align__(16) ushortT Ps[64 * PSTR];  // [local q][kpos] (17 KB)

    int bh = blockIdx.x;
    int b = bh >> 4, h = bh & 15;
    int qi = 15 - blockIdx.y;       // heavy blocks first
    int q0 = qi * 64;
    int tid = threadIdx.x, wave = tid >> 6, lane = tid & 63;
    int col0 = lane & 15, quad = lane >> 4;

    const ushortT* Kbh  = Kb  + ((size_t)bh << 16);
    const ushortT* Vtbh = Vtb + ((size_t)bh << 16);

    const ushortT* qrowp = Qb + ((size_t)bh << 16) + (size_t)(q0 + wave * 16 + col0) * 64;
    bf16x8 aq[2];
    aq[0] = *(const bf16x8*)(qrowp + quad * 8);
    aq[1] = *(const bf16x8*)(qrowp + 32 + quad * 8);

    bf16x8 onesb;
#pragma unroll
    for (int i = 0; i < 8; ++i) onesb[i] = (short)0x3F80;   // bf16 1.0

    f32x4 o[4] = {};
    f32x4 lsum = {};

    int nchunks = qi / 2 + 1;
    for (int cc = 0; cc < nchunks; ++cc) {
        int j0 = cc * 128;
        __syncthreads();
        // stage K (16 KB) and permuted V^T (16 KB)
#pragma unroll
        for (int it = 0; it < 4; ++it) {
            int gci = (wave * 4 + it) * 64 + lane;
            {   // K: rows = key (128), 8 chunks/row
                int r = gci >> 3, c = gci & 7;
                int sc = c ^ (r & 7);
                const ushortT* gk = Kbh + (size_t)(j0 + r) * 64 + sc * 8;
                __builtin_amdgcn_global_load_lds(
                    (const __attribute__((address_space(1))) unsigned int*)gk,
                    (__attribute__((address_space(3))) unsigned int*)(Ks + (wave * 4 + it) * 512),
                    16, 0, 0);
            }
            {   // V: rows = d (64), 16 chunks/row
                int d = gci >> 4, c = gci & 15;
                int sc = c ^ (d & 15);
                const ushortT* gv = Vtbh + (size_t)d * 1024 + j0 + sc * 8;
                __builtin_amdgcn_global_load_lds(
                    (const __attribute__((address_space(1))) unsigned int*)gv,
                    (__attribute__((address_space(3))) unsigned int*)(Vs + (wave * 4 + it) * 512),
                    16, 0, 0);
            }
        }
        __syncthreads();

        // ---- scores: S = Q K^T  (16 q x 128 keys per wave), already in log2 units
        f32x4 sc4[8] = {};
#pragma unroll
        for (int s = 0; s < 2; ++s) {
#pragma unroll
            for (int nt = 0; nt < 8; ++nt) {
                int r = nt * 16 + col0;
                bf16x8 bk = *(const bf16x8*)(Ks + r * 64 + (((s * 4 + quad) ^ (col0 & 7)) * 8));
                sc4[nt] = __builtin_amdgcn_mfma_f32_16x16x32_bf16(aq[s], bk, sc4[nt], 0, 0, 0);
            }
        }

        // ---- fixed-max softmax: p = exp2(s), mask (last chunk only), pack to Ps
        if (cc == nchunks - 1)
            softmax_store<true>(sc4, Ps, wave, quad, col0, q0, j0);
        else
            softmax_store<false>(sc4, Ps, wave, quad, col0, q0, j0);

        // ---- PV: O += P' V'  and  l += P' * ones  (kpos-permuted, consistent)
#pragma unroll
        for (int s = 0; s < 4; ++s) {
            bf16x8 ap = *(const bf16x8*)(Ps + (wave * 16 + col0) * PSTR + s * 32 + quad * 8);
            lsum = __builtin_amdgcn_mfma_f32_16x16x32_bf16(ap, onesb, lsum, 0, 0, 0);
#pragma unroll
            for (int nt = 0; nt < 4; ++nt) {
                int d = nt * 16 + col0;
                bf16x8 bv = *(const bf16x8*)(Vs + d * 128 + (((s * 4 + quad) ^ col0) * 8));
                o[nt] = __builtin_amdgcn_mfma_f32_16x16x32_bf16(ap, bv, o[nt], 0, 0, 0);
            }
        }
    }

    // ---- epilogue
#pragma unroll
    for (int reg = 0; reg < 4; ++reg) {
        int q = q0 + wave * 16 + quad * 4 + reg;
        if (q < T_) {
            float inv_l = 1.0f / lsum[reg];
            ushortT* yp = Yb + (size_t)(b * T_ + q) * 1024 + h * 64;
#pragma unroll
            for (int nt = 0; nt < 4; ++nt)
                yp[nt * 16 + col0] = f2bf(o[nt][reg] * inv_l);
        }
    }
}

extern "C" void kernel_launch(void* const* d_in, const int* in_sizes, int n_in,
                              void* d_out, int out_size, void* d_ws, size_t ws_size,
                              hipStream_t stream) {
    const float* x      = (const float*)d_in[0];
    const float* W_attn = (const float*)d_in[2];
    const float* W_proj = (const float*)d_in[3];
    float* out = (float*)d_out;

    uintptr_t w = (uintptr_t)d_ws;
    ushortT* Xb   = (ushortT*)(w);                   //  8,388,608 B
    ushortT* Wat  = (ushortT*)(w + 8388608);         //  6,291,456 B
    ushortT* Wpt  = (ushortT*)(w + 14680064);        //  2,097,152 B
    ushortT* qkvb = (ushortT*)(w + 16777216);        // 25,165,824 B
    ushortT* Qb   = (ushortT*)(w + 41943040);        //  8,388,608 B
    ushortT* Kb   = (ushortT*)(w + 50331648);        //  8,388,608 B
    ushortT* Vtb  = (ushortT*)(w + 58720256);        //  8,388,608 B
    ushortT* Yb   = (ushortT*)(w + 67108864);        //  8,388,608 B

    cast_x_kernel<<<dim3((MP * C_ / 4 + 255) / 256), dim3(256), 0, stream>>>(x, Xb);
    transpose_w_kernel<<<dim3(3072 / 64, 1024 / 64), dim3(256), 0, stream>>>(W_attn, Wat, 3072);
    transpose_w_kernel<<<dim3(1024 / 64, 1024 / 64), dim3(256), 0, stream>>>(W_proj, Wpt, 1024);

    gemm_bf16_kernel<ushortT><<<dim3(3072 / BN, MP / BM), dim3(256), 0, stream>>>(
        Xb, Wat, qkvb, MP, 3072, 1024, MP);

    rope_pack_kernel<<<dim3(B_ * 1024 * H_ * 32 / 256), dim3(256), 0, stream>>>(qkvb, Qb, Kb);
    vtrans_kernel<<<dim3(8, H_, B_), dim3(256), 0, stream>>>(qkvb, Vtb);

    attn_mfma_kernel<<<dim3(64, 16), dim3(256), 0, stream>>>(Qb, Kb, Vtb, Yb);

    gemm_bf16_kernel<float><<<dim3(1024 / BN, MP / BM), dim3(256), 0, stream>>>(
        Yb, Wpt, out, MP, 1024, 1024, B_ * T_);
}

// Round 4
// 155.279 us; speedup vs baseline: 3.9389x; 1.0925x over previous
//
#include <hip/hip_runtime.h>

typedef unsigned short ushortT;
typedef unsigned int uintT;
typedef __attribute__((ext_vector_type(8))) short bf16x8;
typedef __attribute__((ext_vector_type(4))) float f32x4;

#define B_ 4
#define T_ 1000
#define H_ 16
#define MP 4096
#define QSCALE 0.18033688011112042f   // 0.125 * log2(e)

__device__ __forceinline__ ushortT f2bf(float f) {
    unsigned u = __float_as_uint(f);
    u += 0x7fffu + ((u >> 16) & 1u);   // round-to-nearest-even
    return (ushortT)(u >> 16);
}
__device__ __forceinline__ float fast_exp2(float x) {
#if __has_builtin(__builtin_amdgcn_exp2f)
    return __builtin_amdgcn_exp2f(x);
#else
    return exp2f(x);
#endif
}

// ================ prep: cast x -> Xb (padded rows b*1024+t) + transpose both W
// blocks 0..4095: cast; 4096..4863: W_attn transpose; 4864..5119: W_proj transpose
__global__ void prep_kernel(const float* __restrict__ x,
                            const float* __restrict__ Wa, const float* __restrict__ Wp,
                            ushortT* __restrict__ Xb,
                            ushortT* __restrict__ Wat, ushortT* __restrict__ Wpt) {
    __shared__ float tile[64][65];
    int bid = blockIdx.x, tid = threadIdx.x;
    if (bid < 4096) {
        int e = (bid * 256 + tid) * 4;          // padded element index
        int r = e >> 10, col = e & 1023;
        int b = r >> 10, t = r & 1023;
        ushort4 o = make_ushort4(0, 0, 0, 0);
        if (t < T_) {
            float4 v = *(const float4*)(x + (((size_t)(b * T_ + t)) << 10) + col);
            o.x = f2bf(v.x); o.y = f2bf(v.y); o.z = f2bf(v.z); o.w = f2bf(v.w);
        }
        *(ushort4*)(Xb + (size_t)e) = o;
        return;
    }
    const float* W; ushortT* Wt; int N, bx, by;
    if (bid < 4096 + 768) { W = Wa; Wt = Wat; N = 3072; int id = bid - 4096; bx = id % 48; by = id / 48; }
    else                  { W = Wp; Wt = Wpt; N = 1024; int id = bid - 4864; bx = id & 15; by = id >> 4; }
    int k0 = by * 64, n0 = bx * 64;
    int lane = tid & 63, w4 = tid >> 6;
#pragma unroll 4
    for (int i = 0; i < 16; ++i) {
        int row = i * 4 + w4;
        tile[row][lane] = W[(size_t)(k0 + row) * N + n0 + lane];
    }
    __syncthreads();
#pragma unroll 4
    for (int i = 0; i < 16; ++i) {
        int row = i * 4 + w4;
        Wt[(size_t)(n0 + row) * 1024 + k0 + lane] = f2bf(tile[lane][row]);
    }
}

// ================ QKV GEMM with fused RoPE/pack/V-transpose epilogue
// C-tile 128x128, BK=64, 4 waves 2x2. Columns: sec 0 = q, 1 = k, 2 = v.
__global__ __launch_bounds__(256, 2) void gemm_qkv_kernel(
    const ushortT* __restrict__ A, const ushortT* __restrict__ Bt,
    ushortT* __restrict__ Qb, ushortT* __restrict__ Kb, ushortT* __restrict__ Vtb)
{
    __shared__ __align__(16) ushortT smem[16896];   // 33792 B: As+Bs / sincos tab / transpose buf
    ushortT* As = smem;
    ushortT* Bs = smem + 8192;
    const int K = 1024;
    int tid = threadIdx.x, wave = tid >> 6, lane = tid & 63;
    int m0 = blockIdx.y * 128, n0 = blockIdx.x * 128;
    int wm = (wave >> 1) * 64, wn = (wave & 1) * 64;
    int col0 = lane & 15, quad = lane >> 4;

    f32x4 acc[4][4] = {};

    for (int kt = 0; kt < 16; ++kt) {
        int k0 = kt * 64;
        __syncthreads();
#pragma unroll
        for (int it = 0; it < 4; ++it) {
            int gci = (wave * 4 + it) * 64 + lane;
            int r = gci >> 3, c = gci & 7;
            int sc = c ^ (r & 7);
            const ushortT* ga = A + (size_t)(m0 + r) * K + k0 + sc * 8;
            __builtin_amdgcn_global_load_lds(
                (const __attribute__((address_space(1))) unsigned int*)ga,
                (__attribute__((address_space(3))) unsigned int*)(As + (wave * 4 + it) * 512),
                16, 0, 0);
            const ushortT* gb = Bt + (size_t)(n0 + r) * K + k0 + sc * 8;
            __builtin_amdgcn_global_load_lds(
                (const __attribute__((address_space(1))) unsigned int*)gb,
                (__attribute__((address_space(3))) unsigned int*)(Bs + (wave * 4 + it) * 512),
                16, 0, 0);
        }
        __syncthreads();
#pragma unroll
        for (int s = 0; s < 2; ++s) {
            int g = s * 4 + quad;
            bf16x8 af[4], bfr[4];
#pragma unroll
            for (int mi = 0; mi < 4; ++mi) {
                int r = wm + mi * 16 + col0;
                af[mi] = *(const bf16x8*)(As + r * 64 + ((g ^ (r & 7)) * 8));
            }
#pragma unroll
            for (int ni = 0; ni < 4; ++ni) {
                int r = wn + ni * 16 + col0;
                bfr[ni] = *(const bf16x8*)(Bs + r * 64 + ((g ^ (r & 7)) * 8));
            }
#pragma unroll
            for (int mi = 0; mi < 4; ++mi)
#pragma unroll
                for (int ni = 0; ni < 4; ++ni)
                    acc[mi][ni] = __builtin_amdgcn_mfma_f32_16x16x32_bf16(
                        af[mi], bfr[ni], acc[mi][ni], 0, 0, 0);
        }
    }
    __syncthreads();   // all waves done reading As/Bs before smem reuse

    int sec = n0 >> 10, cb = n0 & 1023;
    int b = m0 >> 10, tbase = m0 & 1023;

    if (sec < 2) {
        // ---- cooperative cos/sin table for this block's 128 t values x 32 p
        float2* tab = (float2*)smem;   // [tl][p], stride 33 (bank-spread)
#pragma unroll
        for (int i = 0; i < 16; ++i) {
            int task = i * 256 + tid;
            int tl = task >> 5, p = task & 31;
            float theta = __expf(-(float)p * 0.28782313662425572f);  // 10000^(-p/32)
            float ang = (float)(tbase + tl) * theta;
            float sn, cs;
            sincosf(ang, &sn, &cs);
            tab[tl * 33 + p] = make_float2(cs, sn);
        }
        __syncthreads();
        ushortT* Out = sec ? Kb : Qb;
        float qs = sec ? 1.0f : QSCALE;
#pragma unroll
        for (int mi = 0; mi < 4; ++mi) {
#pragma unroll
            for (int j = 0; j < 4; ++j) {
                int tl = wm + mi * 16 + quad * 4 + j;
                int t = tbase + tl;
                bool valid = t < T_;
#pragma unroll
                for (int nt = 0; nt < 4; ++nt) {
                    float xv = acc[mi][nt][j];
                    float xp = __shfl_xor(xv, 1);        // pair partner (d^1)
                    int cl = wn + nt * 16 + col0;
                    int d = cl & 63;
                    float2 cssn = tab[tl * 33 + (d >> 1)];
                    float r = (d & 1) ? (xv * cssn.x + xp * cssn.y)
                                      : (xv * cssn.x - xp * cssn.y);
                    r *= qs;
                    if (valid)
                        Out[((size_t)((b << 4) | ((cb + cl) >> 6)) << 16) + (t << 6) + d] = f2bf(r);
                }
            }
        }
    } else {
        // ---- V: LDS transpose + per-128 key permutation pi(r) = (r&15)*8 + (r>>4)
        ushortT* Ls = smem;   // [col 128][stride 132]
#pragma unroll
        for (int mi = 0; mi < 4; ++mi) {
#pragma unroll
            for (int nt = 0; nt < 4; ++nt) {
                int cl = wn + nt * 16 + col0;
                int rb = wm + mi * 16 + quad * 4;
                uintT lo = (uintT)f2bf(acc[mi][nt][0]) | ((uintT)f2bf(acc[mi][nt][1]) << 16);
                uintT hi = (uintT)f2bf(acc[mi][nt][2]) | ((uintT)f2bf(acc[mi][nt][3]) << 16);
                *(uint2*)(Ls + cl * 132 + rb) = make_uint2(lo, hi);
            }
        }
        __syncthreads();
#pragma unroll
        for (int it = 0; it < 8; ++it) {
            int u = it * 256 + tid;
            int cl = u >> 4, c = u & 15;
            int d = cl & 63, h = (cb + cl) >> 6;
            ushortT tmp[8];
#pragma unroll
            for (int j = 0; j < 8; ++j) tmp[j] = Ls[cl * 132 + j * 16 + c];
            *(bf16x8*)(Vtb + (((size_t)((b << 4) | h)) << 16) + ((size_t)d << 10) + tbase + c * 8)
                = *(bf16x8*)tmp;
        }
    }
}

// ================ MFMA flash attention, fixed-max softmax, 128-key chunks (unchanged core)
#define PSTR 136
template <bool LAST>
__device__ __forceinline__ void softmax_store(f32x4* sc4, ushortT* Ps,
                                              int wave, int quad, int col0,
                                              int q0, int j0) {
#pragma unroll
    for (int reg = 0; reg < 4; ++reg) {
        int m = quad * 4 + reg;
        int q = q0 + wave * 16 + m;
        float pv[8];
#pragma unroll
        for (int nt = 0; nt < 8; ++nt) {
            float p = fast_exp2(sc4[nt][reg]);
            if (LAST && (j0 + nt * 16 + col0) > q) p = 0.f;
            pv[nt] = p;
        }
        int4 pk;
        pk.x = __builtin_amdgcn_perm(__float_as_uint(pv[1]), __float_as_uint(pv[0]), 0x07060302u);
        pk.y = __builtin_amdgcn_perm(__float_as_uint(pv[3]), __float_as_uint(pv[2]), 0x07060302u);
        pk.z = __builtin_amdgcn_perm(__float_as_uint(pv[5]), __float_as_uint(pv[4]), 0x07060302u);
        pk.w = __builtin_amdgcn_perm(__float_as_uint(pv[7]), __float_as_uint(pv[6]), 0x07060302u);
        *(int4*)(Ps + (wave * 16 + m) * PSTR + col0 * 8) = pk;
    }
}

__global__ __launch_bounds__(256, 3) void attn_mfma_kernel(
    const ushortT* __restrict__ Qb, const ushortT* __restrict__ Kb,
    const ushortT* __restrict__ Vtb, ushortT* __restrict__ Yb)
{
    __shared__ __align__(16) ushortT Ks[128 * 64];
    __shared__ __align__(16) ushortT Vs[64 * 128];
    __shared__ __align__(16) ushortT Ps[64 * PSTR];

    int bh = blockIdx.x;
    int b = bh >> 4, h = bh & 15;
    int qi = 15 - blockIdx.y;       // heavy blocks first
    int q0 = qi * 64;
    int tid = threadIdx.x, wave = tid >> 6, lane = tid & 63;
    int col0 = lane & 15, quad = lane >> 4;

    const ushortT* Kbh  = Kb  + ((size_t)bh << 16);
    const ushortT* Vtbh = Vtb + ((size_t)bh << 16);

    const ushortT* qrowp = Qb + ((size_t)bh << 16) + (size_t)(q0 + wave * 16 + col0) * 64;
    bf16x8 aq[2];
    aq[0] = *(const bf16x8*)(qrowp + quad * 8);
    aq[1] = *(const bf16x8*)(qrowp + 32 + quad * 8);

    bf16x8 onesb;
#pragma unroll
    for (int i = 0; i < 8; ++i) onesb[i] = (short)0x3F80;

    f32x4 o[4] = {};
    f32x4 lsum = {};

    int nchunks = qi / 2 + 1;
    for (int cc = 0; cc < nchunks; ++cc) {
        int j0 = cc * 128;
        __syncthreads();
#pragma unroll
        for (int it = 0; it < 4; ++it) {
            int gci = (wave * 4 + it) * 64 + lane;
            {
                int r = gci >> 3, c = gci & 7;
                int sc = c ^ (r & 7);
                const ushortT* gk = Kbh + (size_t)(j0 + r) * 64 + sc * 8;
                __builtin_amdgcn_global_load_lds(
                    (const __attribute__((address_space(1))) unsigned int*)gk,
                    (__attribute__((address_space(3))) unsigned int*)(Ks + (wave * 4 + it) * 512),
                    16, 0, 0);
            }
            {
                int d = gci >> 4, c = gci & 15;
                int sc = c ^ (d & 15);
                const ushortT* gv = Vtbh + (size_t)d * 1024 + j0 + sc * 8;
                __builtin_amdgcn_global_load_lds(
                    (const __attribute__((address_space(1))) unsigned int*)gv,
                    (__attribute__((address_space(3))) unsigned int*)(Vs + (wave * 4 + it) * 512),
                    16, 0, 0);
            }
        }
        __syncthreads();

        f32x4 sc4[8] = {};
#pragma unroll
        for (int s = 0; s < 2; ++s) {
#pragma unroll
            for (int nt = 0; nt < 8; ++nt) {
                int r = nt * 16 + col0;
                bf16x8 bk = *(const bf16x8*)(Ks + r * 64 + (((s * 4 + quad) ^ (col0 & 7)) * 8));
                sc4[nt] = __builtin_amdgcn_mfma_f32_16x16x32_bf16(aq[s], bk, sc4[nt], 0, 0, 0);
            }
        }

        if (cc == nchunks - 1)
            softmax_store<true>(sc4, Ps, wave, quad, col0, q0, j0);
        else
            softmax_store<false>(sc4, Ps, wave, quad, col0, q0, j0);

#pragma unroll
        for (int s = 0; s < 4; ++s) {
            bf16x8 ap = *(const bf16x8*)(Ps + (wave * 16 + col0) * PSTR + s * 32 + quad * 8);
            lsum = __builtin_amdgcn_mfma_f32_16x16x32_bf16(ap, onesb, lsum, 0, 0, 0);
#pragma unroll
            for (int nt = 0; nt < 4; ++nt) {
                int d = nt * 16 + col0;
                bf16x8 bv = *(const bf16x8*)(Vs + d * 128 + (((s * 4 + quad) ^ col0) * 8));
                o[nt] = __builtin_amdgcn_mfma_f32_16x16x32_bf16(ap, bv, o[nt], 0, 0, 0);
            }
        }
    }

#pragma unroll
    for (int reg = 0; reg < 4; ++reg) {
        int q = q0 + wave * 16 + quad * 4 + reg;
        if (q < T_) {
            float inv_l = 1.0f / lsum[reg];
            ushortT* yp = Yb + ((size_t)(b * 1024 + q) << 10) + h * 64;   // padded rows
#pragma unroll
            for (int nt = 0; nt < 4; ++nt)
                yp[nt * 16 + col0] = f2bf(o[nt][reg] * inv_l);
        }
    }
}

// ================ Proj GEMM: 64x128 tile (grid 512 = 2 blocks/CU), row-remap fp32 store
__global__ __launch_bounds__(256, 3) void gemm_proj_kernel(
    const ushortT* __restrict__ A, const ushortT* __restrict__ Bt,
    float* __restrict__ Cout)
{
    __shared__ __align__(16) ushortT As[64 * 64];    // 8 KB
    __shared__ __align__(16) ushortT Bs[128 * 64];   // 16 KB
    const int K = 1024;
    int tid = threadIdx.x, wave = tid >> 6, lane = tid & 63;
    int m0 = blockIdx.y * 64, n0 = blockIdx.x * 128;
    int wm = (wave >> 1) * 32, wn = (wave & 1) * 64;
    int col0 = lane & 15, quad = lane >> 4;

    f32x4 acc[2][4] = {};

    for (int kt = 0; kt < 16; ++kt) {
        int k0 = kt * 64;
        __syncthreads();
#pragma unroll
        for (int it = 0; it < 2; ++it) {
            int gci = it * 256 + tid;
            int r = gci >> 3, c = gci & 7;
            int sc = c ^ (r & 7);
            const ushortT* ga = A + (size_t)(m0 + r) * K + k0 + sc * 8;
            __builtin_amdgcn_global_load_lds(
                (const __attribute__((address_space(1))) unsigned int*)ga,
                (__attribute__((address_space(3))) unsigned int*)(As + it * 2048 + wave * 512),
                16, 0, 0);
        }
#pragma unroll
        for (int it = 0; it < 4; ++it) {
            int gci = it * 256 + tid;
            int r = gci >> 3, c = gci & 7;
            int sc = c ^ (r & 7);
            const ushortT* gb = Bt + (size_t)(n0 + r) * K + k0 + sc * 8;
            __builtin_amdgcn_global_load_lds(
                (const __attribute__((address_space(1))) unsigned int*)gb,
                (__attribute__((address_space(3))) unsigned int*)(Bs + it * 2048 + wave * 512),
                16, 0, 0);
        }
        __syncthreads();
#pragma unroll
        for (int s = 0; s < 2; ++s) {
            int g = s * 4 + quad;
            bf16x8 af[2], bfr[4];
#pragma unroll
            for (int mi = 0; mi < 2; ++mi) {
                int r = wm + mi * 16 + col0;
                af[mi] = *(const bf16x8*)(As + r * 64 + ((g ^ (r & 7)) * 8));
            }
#pragma unroll
            for (int ni = 0; ni < 4; ++ni) {
                int r = wn + ni * 16 + col0;
                bfr[ni] = *(const bf16x8*)(Bs + r * 64 + ((g ^ (r & 7)) * 8));
            }
#pragma unroll
            for (int mi = 0; mi < 2; ++mi)
#pragma unroll
                for (int ni = 0; ni < 4; ++ni)
                    acc[mi][ni] = __builtin_amdgcn_mfma_f32_16x16x32_bf16(
                        af[mi], bfr[ni], acc[mi][ni], 0, 0, 0);
        }
    }

#pragma unroll
    for (int mi = 0; mi < 2; ++mi) {
#pragma unroll
        for (int j = 0; j < 4; ++j) {
            int row = m0 + wm + mi * 16 + quad * 4 + j;
            int t = row & 1023, b = row >> 10;
            if (t < T_) {
                float* cp = Cout + ((size_t)(b * T_ + t) << 10) + n0 + wn;
#pragma unroll
                for (int ni = 0; ni < 4; ++ni)
                    cp[ni * 16 + col0] = acc[mi][ni][j];
            }
        }
    }
}

extern "C" void kernel_launch(void* const* d_in, const int* in_sizes, int n_in,
                              void* d_out, int out_size, void* d_ws, size_t ws_size,
                              hipStream_t stream) {
    const float* x      = (const float*)d_in[0];
    const float* W_attn = (const float*)d_in[2];
    const float* W_proj = (const float*)d_in[3];
    float* out = (float*)d_out;

    uintptr_t w = (uintptr_t)d_ws;
    ushortT* Xb  = (ushortT*)(w);                   //  8 MB  bf16 [4096][1024] (padded rows)
    ushortT* Wat = (ushortT*)(w + 8388608);         //  6 MB  bf16 [3072][1024]
    ushortT* Wpt = (ushortT*)(w + 14680064);        //  2 MB  bf16 [1024][1024]
    ushortT* Qb  = (ushortT*)(w + 16777216);        //  8 MB  bf16 [64bh][1024][64]
    ushortT* Kb  = (ushortT*)(w + 25165824);        //  8 MB
    ushortT* Vtb = (ushortT*)(w + 33554432);        //  8 MB  bf16 [64bh][64][1024] (pi-permuted)
    ushortT* Yb  = (ushortT*)(w + 41943040);        //  8 MB  bf16 [4096][1024] (padded rows)
    // total 50,331,648 B

    prep_kernel<<<dim3(5120), dim3(256), 0, stream>>>(x, W_attn, W_proj, Xb, Wat, Wpt);

    gemm_qkv_kernel<<<dim3(24, 32), dim3(256), 0, stream>>>(Xb, Wat, Qb, Kb, Vtb);

    attn_mfma_kernel<<<dim3(64, 16), dim3(256), 0, stream>>>(Qb, Kb, Vtb, Yb);

    gemm_proj_kernel<<<dim3(8, 64), dim3(256), 0, stream>>>(Yb, Wpt, out);
}